// Round 3
// baseline (1179.860 us; speedup 1.0000x reference)
//
#include <hip/hip_runtime.h>

// ParallelLinear: out[e,o,t] = sum_n W[e,o,n] * x[e,n,t] + b[e,o]
// E=10000, N=64, O=64, T=256, all fp32.
//
// One block per edge; thread t owns output column t; x column lives in 64 VGPRs.
// v2: W/b no longer go through the SCALAR pipe (s_load streaming 16 KB/block
// through ~102 SGPRs was the latency bottleneck). W is staged into LDS with one
// coalesced float4 vector pass, then consumed as wave-uniform ds_read_b128
// broadcasts (conflict-free). 16.25 KB LDS -> 4 blocks/CU at launch_bounds(256,4).
// (Resubmitted unchanged: three prior bench attempts failed infra-side; need the
// measurement before iterating further.)

#define N_IN    64
#define O_OUT   64
#define T_STEPS 256

__global__ __launch_bounds__(256, 4) void ParallelLinear_77627238908437_kernel(
    const float* __restrict__ x,   // [E, N, T]
    const float* __restrict__ W,   // [E, O, N]
    const float* __restrict__ b,   // [E, O]
    float* __restrict__ out)       // [E, O, T]
{
    __shared__ float sW[O_OUT * N_IN];   // 16 KB, row-major [o][n]
    __shared__ float sb[O_OUT];          // 256 B

    const int e = blockIdx.x;
    const int t = threadIdx.x;

    const float* __restrict__ xe   = x   + (size_t)e * (N_IN * T_STEPS);
    const float* __restrict__ We   = W   + (size_t)e * (O_OUT * N_IN);
    const float* __restrict__ be   = b   + (size_t)e * O_OUT;
    float* __restrict__       oute = out + (size_t)e * (O_OUT * T_STEPS);

    // --- Stage W (4096 floats = 1024 float4) + b into LDS, coalesced vector loads.
    {
        const float4* __restrict__ Wg = (const float4*)We;
        float4* Ws = (float4*)sW;
#pragma unroll
        for (int i = 0; i < 4; ++i) {
            Ws[t + 256 * i] = Wg[t + 256 * i];
        }
        if (t < O_OUT) sb[t] = be[t];
    }

    // --- x column into registers: coalesced (lane t -> addr n*T + t),
    // 64 independent dword loads issued before the barrier -> deep in flight.
    float xr[N_IN];
#pragma unroll
    for (int n = 0; n < N_IN; ++n) {
        xr[n] = xe[n * T_STEPS + t];
    }

    __syncthreads();

    // --- 4 output rows per step: 4 independent FMA chains (ILP) sharing xr[n].
    // W reads are wave-uniform ds_read_b128 broadcasts: no bank conflicts.
    for (int o = 0; o < O_OUT; o += 4) {
        float a0 = sb[o + 0];
        float a1 = sb[o + 1];
        float a2 = sb[o + 2];
        float a3 = sb[o + 3];
        const float4* __restrict__ r0 = (const float4*)&sW[(o + 0) * N_IN];
        const float4* __restrict__ r1 = (const float4*)&sW[(o + 1) * N_IN];
        const float4* __restrict__ r2 = (const float4*)&sW[(o + 2) * N_IN];
        const float4* __restrict__ r3 = (const float4*)&sW[(o + 3) * N_IN];
#pragma unroll
        for (int q = 0; q < N_IN / 4; ++q) {
            const float4 w0 = r0[q];
            const float4 w1 = r1[q];
            const float4 w2 = r2[q];
            const float4 w3 = r3[q];
            const float x0 = xr[4 * q + 0];
            const float x1 = xr[4 * q + 1];
            const float x2 = xr[4 * q + 2];
            const float x3 = xr[4 * q + 3];
            a0 = fmaf(w0.x, x0, a0); a0 = fmaf(w0.y, x1, a0);
            a0 = fmaf(w0.z, x2, a0); a0 = fmaf(w0.w, x3, a0);
            a1 = fmaf(w1.x, x0, a1); a1 = fmaf(w1.y, x1, a1);
            a1 = fmaf(w1.z, x2, a1); a1 = fmaf(w1.w, x3, a1);
            a2 = fmaf(w2.x, x0, a2); a2 = fmaf(w2.y, x1, a2);
            a2 = fmaf(w2.z, x2, a2); a2 = fmaf(w2.w, x3, a2);
            a3 = fmaf(w3.x, x0, a3); a3 = fmaf(w3.y, x1, a3);
            a3 = fmaf(w3.z, x2, a3); a3 = fmaf(w3.w, x3, a3);
        }
        oute[(o + 0) * T_STEPS + t] = a0;
        oute[(o + 1) * T_STEPS + t] = a1;
        oute[(o + 2) * T_STEPS + t] = a2;
        oute[(o + 3) * T_STEPS + t] = a3;
    }
}

extern "C" void kernel_launch(void* const* d_in, const int* in_sizes, int n_in,
                              void* d_out, int out_size, void* d_ws, size_t ws_size,
                              hipStream_t stream) {
    const float* x = (const float*)d_in[0];
    const float* W = (const float*)d_in[1];
    const float* b = (const float*)d_in[2];
    float* out = (float*)d_out;

    const int E = in_sizes[0] / (N_IN * T_STEPS);  // 10000

    dim3 grid(E);
    dim3 block(T_STEPS);
    ParallelLinear_77627238908437_kernel<<<grid, block, 0, stream>>>(x, W, b, out);
}